// Round 5
// baseline (5468.492 us; speedup 1.0000x reference)
//
#include <hip/hip_runtime.h>
#include <hip/hip_fp16.h>

#define LOG2E 1.44269504088896340736f
#define BB 256
#define TT 128
#define SS 128
#define UU 256
// |dv| threshold for "unfold was identity" (see R1/R2 notes: must sit above 1 f16 ulp
// of v in [0.5,1) = 4.88e-4 to absorb f16 fixed-point dither).
#define CONV_EPS 6.0e-4f

typedef unsigned int u32;

__device__ __forceinline__ __half2 uh(u32 x) { union { u32 u; __half2 h; } c; c.u = x; return c.h; }
__device__ __forceinline__ u32 hu(__half2 h) { union { u32 u; __half2 h2; } c; c.h2 = h; return c.u; }

// ---------------- parameter precompute (pair-packed) ----------------
// sigmoid(sigma*(v-mu)) = 1/(1+2^(a*v+b)), a=-sigma*log2e, b=sigma*mu*log2e
// Two consecutive pre-rows (2*i2, 2*i2+1) packed per entry:
//   uint4{ half2(a0,a1), half2(b0,b1), half2(wP0,wP1), half2(wN0,wN1) }  (16 B)
__global__ __launch_bounds__(256) void prep_kernel(
    const float* __restrict__ sensory_w, const float* __restrict__ sensory_mu,
    const float* __restrict__ sensory_sigma, const float* __restrict__ sensory_erev,
    const float* __restrict__ w, const float* __restrict__ mu,
    const float* __restrict__ sigma, const float* __restrict__ erev,
    const float* __restrict__ gleak, const float* __restrict__ vleak,
    const float* __restrict__ cm,
    uint4* __restrict__ rabw4, uint4* __restrict__ sabw4,
    float* __restrict__ cmt, float* __restrict__ gnum, float* __restrict__ cden)
{
    int e = blockIdx.x * 256 + threadIdx.x;   // e = i2*256 + j
    if (e < (UU / 2) * UU) {
        int i2 = e >> 8, j = e & 255;
        int r0 = (2 * i2) * UU + j, r1 = r0 + UU;
        float sg0 = sigma[r0], sg1 = sigma[r1];
        float m0 = mu[r0], m1 = mu[r1];
        float wq0 = log1pf(expf(w[r0])), wq1 = log1pf(expf(w[r1]));
        bool p0 = erev[r0] > 0.0f, p1 = erev[r1] > 0.0f;
        uint4 o;
        o.x = hu(__floats2half2_rn(-sg0 * LOG2E, -sg1 * LOG2E));
        o.y = hu(__floats2half2_rn(sg0 * m0 * LOG2E, sg1 * m1 * LOG2E));
        o.z = hu(__floats2half2_rn(p0 ? wq0 : 0.0f, p1 ? wq1 : 0.0f));
        o.w = hu(__floats2half2_rn(p0 ? 0.0f : wq0, p1 ? 0.0f : wq1));
        rabw4[e] = o;
    }
    if (e < (SS / 2) * UU) {
        int i2 = e >> 8, j = e & 255;
        int r0 = (2 * i2) * UU + j, r1 = r0 + UU;
        float sg0 = sensory_sigma[r0], sg1 = sensory_sigma[r1];
        float m0 = sensory_mu[r0], m1 = sensory_mu[r1];
        float wq0 = log1pf(expf(sensory_w[r0])), wq1 = log1pf(expf(sensory_w[r1]));
        bool p0 = sensory_erev[r0] > 0.0f, p1 = sensory_erev[r1] > 0.0f;
        uint4 o;
        o.x = hu(__floats2half2_rn(-sg0 * LOG2E, -sg1 * LOG2E));
        o.y = hu(__floats2half2_rn(sg0 * m0 * LOG2E, sg1 * m1 * LOG2E));
        o.z = hu(__floats2half2_rn(p0 ? wq0 : 0.0f, p1 ? wq1 : 0.0f));
        o.w = hu(__floats2half2_rn(p0 ? 0.0f : wq0, p1 ? 0.0f : wq1));
        sabw4[e] = o;
    }
    if (e < UU) {
        float gl = log1pf(expf(gleak[e]));
        float c = log1pf(expf(cm[e])) * 6.0f;   // ODE_UNFOLDS=6, ts=1
        cmt[e] = c;
        gnum[e] = gl * vleak[e];
        cden[e] = c + gl + 1e-8f;
    }
}

// Packed 2-row sigmoid-weighted accumulation, NO transcendentals.
// exp2 via magic-rounding + deg-3 poly + integer exponent splice
//   (0x6600<<10 == 0 mod 2^16, so ebits = bits(z+1536)<<10 directly).
// rcp via magic seed 0x77AB - bits(d) + 2 packed Newton iterations.
// z clamped to [-13.5,13.5]: keeps e=2^z and 1/d in f16-normal range.
//
// R4 failure root-cause fixes:
//  (1) VOP3P inline-constant hazard: `v_pk_lshlrev_b16 d, 10, s` encodes 10 as a
//      32-bit inline constant; default op_sel_hi makes the HI half read bits[31:16]
//      = 0 -> hi-lane shift corrupted -> splice garbage -> d<=0 -> negative/huge
//      reciprocals -> v explodes (absmax 468). Shift amount now lives in a VGPR
//      holding packed 0x000A000A so both halves shift by 10.
//  (2) defense-in-depth: e2 = pk_max(e2, 0) guarantees d>=1 -> rr in (0,1] ->
//      explosion structurally impossible (no-op on all correct paths; inline 0 is
//      safe since its hi 16 bits are also 0).
#define STEP2(A2U, B2U, WP2U, WN2U, V2U) do {                                \
    __half2 z2_ = __hfma2(uh(A2U), uh(V2U), uh(B2U));                        \
    u32 zcu_;                                                                \
    asm("v_pk_max_f16 %0, %1, %2" : "=v"(zcu_) : "v"(hu(z2_)), "v"(kLOv));   \
    asm("v_pk_min_f16 %0, %1, %2" : "=v"(zcu_) : "v"(zcu_), "v"(kHIv));      \
    __half2 zc_ = uh(zcu_);                                                  \
    __half2 mm_ = __hadd2(zc_, cMAGIC);                                      \
    __half2 zr_ = __hsub2(mm_, cMAGIC);                                      \
    __half2 ff_ = __hsub2(zc_, zr_);                                         \
    __half2 pp_ = __hfma2(ff_, cC3, cC2);                                    \
    pp_ = __hfma2(ff_, pp_, cC1);                                            \
    pp_ = __hfma2(ff_, pp_, cC0);                                            \
    u32 eb_, e2_;                                                            \
    asm("v_pk_lshlrev_b16 %0, %1, %2" : "=v"(eb_) : "v"(kSHv), "v"(hu(mm_)));\
    asm("v_pk_add_u16 %0, %1, %2" : "=v"(e2_) : "v"(hu(pp_)), "v"(eb_));     \
    asm("v_pk_max_f16 %0, %1, 0" : "=v"(e2_) : "v"(e2_));                    \
    __half2 d2_ = __hadd2(uh(e2_), cONE);                                    \
    u32 r0u_;                                                                \
    asm("v_pk_sub_u16 %0, %1, %2" : "=v"(r0u_) : "v"(kRCPv), "v"(hu(d2_)));  \
    __half2 rr_ = uh(r0u_);                                                  \
    rr_ = __hmul2(rr_, __hsub2(cTWO, __hmul2(d2_, rr_)));                    \
    rr_ = __hmul2(rr_, __hsub2(cTWO, __hmul2(d2_, rr_)));                    \
    accP2 = __hfma2(uh(WP2U), rr_, accP2);                                   \
    accN2 = __hfma2(uh(WN2U), rr_, accN2);                                   \
} while (0)

#define FLUSH2() do {                                                        \
    float2 fp_ = __half22float2(accP2);                                      \
    float2 fn_ = __half22float2(accN2);                                      \
    P += fp_.x + fp_.y; N += fn_.x + fn_.y;                                  \
    accP2 = uh(0u); accN2 = uh(0u);                                          \
} while (0)

// ---------------- main kernel: 1 block = 1 batch element, 16 waves ----------------
// wave (qi=wv&3, qj=wv>>2): column j = 64*qj + l.
// i-rows per wave: 48 in registers (rows 48qi..+47 = pairs 24qi..+23) + 16 from LDS
// (rows 192+16qi..+15 = pairs 96+8qi..+7). v lane-distributed as before; pair-packed
// v broadcast built once per unfold with one shfl_xor (even lane l holds
// (v[u(l)],v[u(l+1)]) packed), then one readlane feeds each 2-row STEP2.
__global__ __launch_bounds__(1024, 4) void ltc_kernel(
    const float* __restrict__ x,
    const float* __restrict__ input_w, const float* __restrict__ input_b,
    const float* __restrict__ halt_w, const float* __restrict__ halt_b,
    const float* __restrict__ out_w, const float* __restrict__ out_b,
    const uint4* __restrict__ rabw4, const uint4* __restrict__ sabw4,
    const float* __restrict__ cmt_g, const float* __restrict__ gnum_g,
    const float* __restrict__ cden_g,
    float* __restrict__ readout, float* __restrict__ h_state, float* __restrict__ ponder_out)
{
    const int b = blockIdx.x, tid = threadIdx.x;
    const int wv = tid >> 6, l = tid & 63;
    const int qi = wv & 3, qj = wv >> 2;
    const int j = (qj << 6) + l;
    const int u = (l < 48) ? (48 * qi + l) : (192 + 16 * qi + (l - 48));

    __shared__ uint4 rlds4[32 * UU];         // 128 KB: row-pairs 96..127 (rows 192..255)
    __shared__ float2 part[2][4][UU];        // 16 KB: (P,N) partials, double-buffered
    __shared__ __half2 xinh2[SS / 2];
    __shared__ float red[4];
    __shared__ int viol[3];                  // triple-buffered "unfold changed v" flag

    // bit-trick constants (loop-invariant, hoisted to regs)
    const u32 kLOv = 0xCAC0CAC0u;            // half2(-13.5, -13.5)
    const u32 kHIv = 0x4AC04AC0u;            // half2(+13.5, +13.5)
    const u32 kSHv = 0x000A000Au;            // packed shift amount (10,10)
    const __half2 cMAGIC = __floats2half2_rn(1536.0f, 1536.0f);
    const __half2 cONE = __floats2half2_rn(1.0f, 1.0f);
    const __half2 cTWO = __floats2half2_rn(2.0f, 2.0f);
    const __half2 cC0 = __floats2half2_rn(1.000303f, 1.000303f);
    const __half2 cC1 = __floats2half2_rn(0.693951f, 0.693951f);
    const __half2 cC2 = __floats2half2_rn(0.240164f, 0.240164f);
    const __half2 cC3 = __floats2half2_rn(0.055828f, 0.055828f);
    const u32 kRCPv = 0x77AB77ABu;

    // stage LDS-resident row-pairs (once): 32*256 uint4
    for (int m = 0; m < 8; ++m) {
        int f = m * 1024 + tid;
        rlds4[f] = rabw4[96 * 256 + f];
    }

    // register-resident row-pairs (once): 96 VGPRs
    u32 rp_a2[24], rp_b2[24], rp_wp2[24], rp_wn2[24];
#pragma unroll
    for (int kk = 0; kk < 24; ++kk) {
        uint4 tp = rabw4[((24 * qi + kk) << 8) + j];
        rp_a2[kk] = tp.x; rp_b2[kk] = tp.y; rp_wp2[kk] = tp.z; rp_wn2[kk] = tp.w;
    }

    const float cmtu = cmt_g[u], gnu = gnum_g[u], cdu = cden_g[u];
    const float hwu = halt_w[u], owu = out_w[u], obu = out_b[u];
    const float hb = halt_b[0];
    float iw = 0.f, ibv = 0.f;
    if (tid < SS) { iw = input_w[tid]; ibv = input_b[tid]; }

    float v = 0.0f;
    int vhb = 0;                  // f16 bits of v (for readlane broadcast)
    float pond = 0.0f;
    __syncthreads();

    for (int t = 0; t < TT; ++t) {
        // ---- input mapping (f16 for broadcast use) ----
        if (tid < SS)
            ((__half*)xinh2)[tid] =
                __float2half(fmaf(x[((size_t)b * TT + t) * SS + tid], iw, ibv));
        __syncthreads();
        if (tid == 0) viol[0] = 0;

        // ---- sensory partials: row-pairs [16qi, 16qi+16), streamed from L2 ----
        {
            float P = 0.f, N = 0.f;
            __half2 accP2 = uh(0u), accN2 = uh(0u);
#pragma unroll 1
            for (int c = 0; c < 8; ++c) {
                int p0 = 16 * qi + 2 * c;
                uint4 q0 = sabw4[(p0 << 8) + j];
                uint4 q1 = sabw4[((p0 + 1) << 8) + j];
                u32 x0 = hu(xinh2[p0]);
                u32 x1 = hu(xinh2[p0 + 1]);
                STEP2(q0.x, q0.y, q0.z, q0.w, x0);
                STEP2(q1.x, q1.y, q1.z, q1.w, x1);
                if ((c & 3) == 3) FLUSH2();
            }
            part[0][qi][j] = make_float2(P, N);
        }
        __syncthreads();
        float basen, based;
        {
            float2 s0 = part[0][0][u], s1 = part[0][1][u];
            float2 s2 = part[0][2][u], s3 = part[0][3][u];
            float Ps = s0.x + s1.x + s2.x + s3.x;
            float Ns = s0.y + s1.y + s2.y + s3.y;
            basen = (Ps - Ns) + gnu;
            based = (Ps + Ns) + cdu;
        }

        int pb = 1;
        float accA = 0.0f, halt_sum = 0.0f, rem = 0.0f;
        int nupd = 0;
        int g3 = 0, g = 0;
        bool tconv = false;
        float pr = 0.0f;

        // ---- ACT loop (uniform early exit) ----
#pragma unroll 1
        for (int n = 0; n < 10; ++n) {
            bool ran = !tconv;
            if (ran) {
#pragma unroll 1
                for (int uu = 0; uu < 6 && !tconv; ++uu) {
                    // pair-packed v broadcast: even lane l holds (v[u(l)], v[u(l+1)])
                    int nbv = __shfl_xor(vhb, 1, 64);
                    int vpk = (vhb & 0xffff) | (nbv << 16);

                    float P = 0.f, N = 0.f;
                    __half2 accP2 = uh(0u), accN2 = uh(0u);
#pragma unroll
                    for (int kk = 0; kk < 24; ++kk) {
                        u32 v2 = (u32)__builtin_amdgcn_readlane(vpk, 2 * kk);
                        STEP2(rp_a2[kk], rp_b2[kk], rp_wp2[kk], rp_wn2[kk], v2);
                        if ((kk & 7) == 7) FLUSH2();
                    }
#pragma unroll
                    for (int m = 0; m < 8; ++m) {
                        uint4 prr = rlds4[((8 * qi + m) << 8) + j];
                        u32 v2 = (u32)__builtin_amdgcn_readlane(vpk, 48 + 2 * m);
                        STEP2(prr.x, prr.y, prr.z, prr.w, v2);
                    }
                    FLUSH2();
                    part[pb][qi][j] = make_float2(P, N);
                    __syncthreads();
                    // redundant per-wave v-update for own units
                    float2 p0 = part[pb][0][u], p1 = part[pb][1][u];
                    float2 p2 = part[pb][2][u], p3 = part[pb][3][u];
                    float Pt = p0.x + p1.x + p2.x + p3.x;
                    float Nt = p0.y + p1.y + p2.y + p3.y;
                    float num = (Pt - Nt) + basen;
                    float den = (Pt + Nt) + based;
                    float vn = fmaf(cmtu, v, num) * __builtin_amdgcn_rcpf(den);
                    float dv = fabsf(vn - v);
                    v = vn;
                    vhb = (int)__half_as_ushort(__float2half(v));
                    // convergence bookkeeping (triple-buffered flag, lag 1)
                    int aw = __all(dv <= CONV_EPS);
                    if (l == 0 && !aw) viol[g3] = 1;
                    int gz = g3 + 1; if (gz == 3) gz = 0;
                    if (tid == 0) viol[gz] = 0;
                    if (g >= 1) {
                        int gr = g3 - 1; if (gr < 0) gr = 2;
                        if (viol[gr] == 0) tconv = true;
                    }
                    pb ^= 1; ++g; g3 = gz;
                }

                // halting p = sigmoid(v . halt_w + hb); qj==0 waves hold all 256 units
                if (qj == 0) {
                    float hp = v * hwu;
                    hp += __shfl_down(hp, 32, 64);
                    hp += __shfl_down(hp, 16, 64);
                    hp += __shfl_down(hp, 8, 64);
                    hp += __shfl_down(hp, 4, 64);
                    hp += __shfl_down(hp, 2, 64);
                    hp += __shfl_down(hp, 1, 64);
                    if (l == 0) red[qi] = hp;
                }
                __syncthreads();
                float dot = red[0] + red[1] + red[2] + red[3] + hb;
                pr = __builtin_amdgcn_rcpf(1.0f + __builtin_amdgcn_exp2f(-dot * LOG2E));
            }
            // scalar ACT accounting (exact reference semantics)
            float new_sum = halt_sum + pr;
            bool halting = (n == 9) || (new_sum >= 0.99f);
            float r = 1.0f - halt_sum;
            float wgt = halting ? r : pr;
            accA = fmaf(wgt, v, accA);
            if (halting) rem += r;
            halt_sum = new_sum;
            ++nupd;
            if (halting) break;
        }

        // ---- t epilogue: new_state = accA ----
        if (qj == 0)
            readout[((size_t)b * TT + t) * UU + u] = fmaf(accA, owu, obu);
        v = accA;
        vhb = (int)__half_as_ushort(__float2half(v));
        pond += (float)nupd + rem;
    }

    if (qj == 0) h_state[(size_t)b * UU + u] = v;
    if (tid == 0) atomicAdd(ponder_out, pond * (1.0f / BB));
}

// ---------------- launch ----------------
extern "C" void kernel_launch(void* const* d_in, const int* in_sizes, int n_in,
                              void* d_out, int out_size, void* d_ws, size_t ws_size,
                              hipStream_t stream)
{
    const float* x             = (const float*)d_in[0];
    const float* input_w       = (const float*)d_in[1];
    const float* input_b       = (const float*)d_in[2];
    const float* sensory_w     = (const float*)d_in[3];
    const float* sensory_mu    = (const float*)d_in[4];
    const float* sensory_sigma = (const float*)d_in[5];
    const float* sensory_erev  = (const float*)d_in[6];
    const float* w             = (const float*)d_in[7];
    const float* mu            = (const float*)d_in[8];
    const float* sigma         = (const float*)d_in[9];
    const float* erev          = (const float*)d_in[10];
    const float* gleak         = (const float*)d_in[11];
    const float* vleak         = (const float*)d_in[12];
    const float* cm            = (const float*)d_in[13];
    const float* output_w      = (const float*)d_in[14];
    const float* output_b      = (const float*)d_in[15];
    const float* halt_w        = (const float*)d_in[16];
    const float* halt_b        = (const float*)d_in[17];

    float* readout = (float*)d_out;
    float* h_state = readout + (size_t)BB * TT * UU;
    float* ponder  = h_state + (size_t)BB * UU;

    char* wsb = (char*)d_ws;
    uint4* rabw4 = (uint4*)wsb;  wsb += (size_t)(UU / 2) * UU * sizeof(uint4);
    uint4* sabw4 = (uint4*)wsb;  wsb += (size_t)(SS / 2) * UU * sizeof(uint4);
    float* cmt  = (float*)wsb;  wsb += (size_t)UU * 4;
    float* gnum = (float*)wsb;  wsb += (size_t)UU * 4;
    float* cden = (float*)wsb;  wsb += (size_t)UU * 4;

    (void)hipMemsetAsync(ponder, 0, sizeof(float), stream);
    prep_kernel<<<128, 256, 0, stream>>>(
        sensory_w, sensory_mu, sensory_sigma, sensory_erev,
        w, mu, sigma, erev, gleak, vleak, cm,
        rabw4, sabw4, cmt, gnum, cden);
    ltc_kernel<<<BB, 1024, 0, stream>>>(
        x, input_w, input_b, halt_w, halt_b, output_w, output_b,
        rabw4, sabw4, cmt, gnum, cden,
        readout, h_state, ponder);
}

// Round 6
// 5423.790 us; speedup vs baseline: 1.0082x; 1.0082x over previous
//
#include <hip/hip_runtime.h>
#include <hip/hip_fp16.h>

#define LOG2E 1.44269504088896340736f
#define BB 256
#define TT 128
#define SS 128
#define UU 256
// |dv| threshold for "unfold was identity" (see R1/R2 notes: must sit above 1 f16 ulp
// of v in [0.5,1) = 4.88e-4 to absorb f16 fixed-point dither).
#define CONV_EPS 6.0e-4f

typedef unsigned int u32;

__device__ __forceinline__ __half2 uh(u32 x) { union { u32 u; __half2 h; } c; c.u = x; return c.h; }
__device__ __forceinline__ u32 hu(__half2 h) { union { u32 u; __half2 h2; } c; c.h2 = h; return c.u; }

// ---------------- parameter precompute (pair-packed) ----------------
// sigmoid(sigma*(v-mu)) = 1/(1+2^(a*v+b)), a=-sigma*log2e, b=sigma*mu*log2e
// Two consecutive pre-rows (2*i2, 2*i2+1) packed per entry:
//   uint4{ half2(a0,a1), half2(b0,b1), half2(wP0,wP1), half2(wN0,wN1) }  (16 B)
__global__ __launch_bounds__(256) void prep_kernel(
    const float* __restrict__ sensory_w, const float* __restrict__ sensory_mu,
    const float* __restrict__ sensory_sigma, const float* __restrict__ sensory_erev,
    const float* __restrict__ w, const float* __restrict__ mu,
    const float* __restrict__ sigma, const float* __restrict__ erev,
    const float* __restrict__ gleak, const float* __restrict__ vleak,
    const float* __restrict__ cm,
    uint4* __restrict__ rabw4, uint4* __restrict__ sabw4,
    float* __restrict__ cmt, float* __restrict__ gnum, float* __restrict__ cden)
{
    int e = blockIdx.x * 256 + threadIdx.x;   // e = i2*256 + j
    if (e < (UU / 2) * UU) {
        int i2 = e >> 8, j = e & 255;
        int r0 = (2 * i2) * UU + j, r1 = r0 + UU;
        float sg0 = sigma[r0], sg1 = sigma[r1];
        float m0 = mu[r0], m1 = mu[r1];
        float wq0 = log1pf(expf(w[r0])), wq1 = log1pf(expf(w[r1]));
        bool p0 = erev[r0] > 0.0f, p1 = erev[r1] > 0.0f;
        uint4 o;
        o.x = hu(__floats2half2_rn(-sg0 * LOG2E, -sg1 * LOG2E));
        o.y = hu(__floats2half2_rn(sg0 * m0 * LOG2E, sg1 * m1 * LOG2E));
        o.z = hu(__floats2half2_rn(p0 ? wq0 : 0.0f, p1 ? wq1 : 0.0f));
        o.w = hu(__floats2half2_rn(p0 ? 0.0f : wq0, p1 ? 0.0f : wq1));
        rabw4[e] = o;
    }
    if (e < (SS / 2) * UU) {
        int i2 = e >> 8, j = e & 255;
        int r0 = (2 * i2) * UU + j, r1 = r0 + UU;
        float sg0 = sensory_sigma[r0], sg1 = sensory_sigma[r1];
        float m0 = sensory_mu[r0], m1 = sensory_mu[r1];
        float wq0 = log1pf(expf(sensory_w[r0])), wq1 = log1pf(expf(sensory_w[r1]));
        bool p0 = sensory_erev[r0] > 0.0f, p1 = sensory_erev[r1] > 0.0f;
        uint4 o;
        o.x = hu(__floats2half2_rn(-sg0 * LOG2E, -sg1 * LOG2E));
        o.y = hu(__floats2half2_rn(sg0 * m0 * LOG2E, sg1 * m1 * LOG2E));
        o.z = hu(__floats2half2_rn(p0 ? wq0 : 0.0f, p1 ? wq1 : 0.0f));
        o.w = hu(__floats2half2_rn(p0 ? 0.0f : wq0, p1 ? 0.0f : wq1));
        sabw4[e] = o;
    }
    if (e < UU) {
        float gl = log1pf(expf(gleak[e]));
        float c = log1pf(expf(cm[e])) * 6.0f;   // ODE_UNFOLDS=6, ts=1
        cmt[e] = c;
        gnum[e] = gl * vleak[e];
        cden[e] = c + gl + 1e-8f;
    }
}

// Packed 2-row sigmoid-weighted accumulation, NO transcendentals.
// exp2 via magic-rounding + deg-3 poly + integer exponent splice; rcp via magic seed
// + 2 packed Newton iterations (math verified end-to-end in R5, absmax 0.00195).
//
// R6 register-pressure rework (R5 spilled past the 128-VGPR/wave cap of the
// 1024-thread block -> 334 MB of HBM scratch writebacks):
//  - every constant-consuming op is inline asm with the constant in an SGPR
//    ("s" constraint; <=1 SGPR read per vector instr). Only C3 stays in a VGPR
//    (first poly fma needs two constants).
//  - zr = m - 1536 via adding packed -1536 (kNMG); Newton n = 2 - d*rr via
//    v_pk_fma_f16 with neg_lo/neg_hi on src0.
//  - e2 = pk_max(e2, 0) guard keeps d>=1 -> rr in (0,1] (explosion impossible).
#define STEP2(A2U, B2U, WP2U, WN2U, V2U) do {                                  \
    u32 z_, m_, f_, p_, e_, d_, r_, n_;                                        \
    z_ = hu(__hfma2(uh(A2U), uh(V2U), uh(B2U)));                               \
    asm("v_pk_max_f16 %0, %1, %2" : "=v"(z_) : "v"(z_), "s"(kLO));             \
    asm("v_pk_min_f16 %0, %1, %2" : "=v"(z_) : "v"(z_), "s"(kHI));             \
    asm("v_pk_add_f16 %0, %1, %2" : "=v"(m_) : "v"(z_), "s"(kMAG));            \
    asm("v_pk_add_f16 %0, %1, %2" : "=v"(f_) : "v"(m_), "s"(kNMG));            \
    f_ = hu(__hsub2(uh(z_), uh(f_)));          /* f = z - round(z), exact */   \
    asm("v_pk_fma_f16 %0, %1, %2, %3" : "=v"(p_) : "v"(f_), "v"(vC3), "s"(kC2)); \
    asm("v_pk_fma_f16 %0, %1, %2, %3" : "=v"(p_) : "v"(f_), "v"(p_), "s"(kC1)); \
    asm("v_pk_fma_f16 %0, %1, %2, %3" : "=v"(p_) : "v"(f_), "v"(p_), "s"(kC0)); \
    asm("v_pk_lshlrev_b16 %0, %1, %2" : "=v"(e_) : "s"(kSH), "v"(m_));         \
    asm("v_pk_add_u16 %0, %1, %2" : "=v"(e_) : "v"(p_), "v"(e_));              \
    asm("v_pk_max_f16 %0, %1, 0" : "=v"(e_) : "v"(e_));                        \
    asm("v_pk_add_f16 %0, %1, %2" : "=v"(d_) : "v"(e_), "s"(kONE));            \
    asm("v_pk_sub_u16 %0, %1, %2" : "=v"(r_) : "s"(kRCP), "v"(d_));            \
    asm("v_pk_fma_f16 %0, %1, %2, %3 neg_lo:[1,0,0] neg_hi:[1,0,0]"            \
        : "=v"(n_) : "v"(d_), "v"(r_), "s"(kTWO));                             \
    r_ = hu(__hmul2(uh(r_), uh(n_)));                                          \
    asm("v_pk_fma_f16 %0, %1, %2, %3 neg_lo:[1,0,0] neg_hi:[1,0,0]"            \
        : "=v"(n_) : "v"(d_), "v"(r_), "s"(kTWO));                             \
    r_ = hu(__hmul2(uh(r_), uh(n_)));                                          \
    accP2 = __hfma2(uh(WP2U), uh(r_), accP2);                                  \
    accN2 = __hfma2(uh(WN2U), uh(r_), accN2);                                  \
} while (0)

#define FLUSH2() do {                                                        \
    float2 fp_ = __half22float2(accP2);                                      \
    float2 fn_ = __half22float2(accN2);                                      \
    P += fp_.x + fp_.y; N += fn_.x + fn_.y;                                  \
    accP2 = uh(0u); accN2 = uh(0u);                                          \
} while (0)

// ---------------- main kernel: 1 block = 1 batch element, 16 waves ----------------
// wave (qi=wv&3, qj=wv>>2): column j = 64*qj + l.
// Recurrent row-pairs per wave (24 total, global pairs 24qi..24qi+23):
//   pairs 0..19 in registers (80 VGPRs), pairs 20..23 streamed from L2 each unfold,
//   plus 8 pairs (rows 192+16qi..+15) from LDS. v lane-distributed; pair-packed v
//   broadcast built once per unfold with one shfl_xor; readlane feeds each STEP2.
__global__ __launch_bounds__(1024, 4) void ltc_kernel(
    const float* __restrict__ x,
    const float* __restrict__ input_w, const float* __restrict__ input_b,
    const float* __restrict__ halt_w, const float* __restrict__ halt_b,
    const float* __restrict__ out_w, const float* __restrict__ out_b,
    const uint4* __restrict__ rabw4, const uint4* __restrict__ sabw4,
    const float* __restrict__ cmt_g, const float* __restrict__ gnum_g,
    const float* __restrict__ cden_g,
    float* __restrict__ readout, float* __restrict__ h_state, float* __restrict__ ponder_out)
{
    const int b = blockIdx.x, tid = threadIdx.x;
    const int wv = tid >> 6, l = tid & 63;
    const int qi = wv & 3, qj = wv >> 2;
    const int j = (qj << 6) + l;
    const int u = (l < 48) ? (48 * qi + l) : (192 + 16 * qi + (l - 48));

    __shared__ uint4 rlds4[32 * UU];         // 128 KB: row-pairs 96..127 (rows 192..255)
    __shared__ float2 part[2][4][UU];        // 16 KB: (P,N) partials, double-buffered
    __shared__ __half2 xinh2[SS / 2];
    __shared__ float red[4];
    __shared__ int viol[3];                  // triple-buffered "unfold changed v" flag

    // packed-math constants: SGPR-resident (see STEP2), C3 in one VGPR
    const u32 kLO  = hu(__floats2half2_rn(-13.5f, -13.5f));
    const u32 kHI  = hu(__floats2half2_rn(13.5f, 13.5f));
    const u32 kMAG = hu(__floats2half2_rn(1536.0f, 1536.0f));
    const u32 kNMG = hu(__floats2half2_rn(-1536.0f, -1536.0f));
    const u32 kC2  = hu(__floats2half2_rn(0.240164f, 0.240164f));
    const u32 kC1  = hu(__floats2half2_rn(0.693951f, 0.693951f));
    const u32 kC0  = hu(__floats2half2_rn(1.000303f, 1.000303f));
    const u32 kONE = hu(__floats2half2_rn(1.0f, 1.0f));
    const u32 kTWO = hu(__floats2half2_rn(2.0f, 2.0f));
    const u32 kSH  = 0x000A000Au;            // packed shift amount (10,10)
    const u32 kRCP = 0x77AB77ABu;            // packed rcp magic seed
    const u32 vC3  = hu(__floats2half2_rn(0.055828f, 0.055828f));

    // stage LDS-resident row-pairs (once): 32*256 uint4
    for (int m = 0; m < 8; ++m) {
        int f = m * 1024 + tid;
        rlds4[f] = rabw4[96 * 256 + f];
    }

    // register-resident row-pairs (once): 80 VGPRs (pairs 24qi..24qi+19)
    u32 rp_a2[20], rp_b2[20], rp_wp2[20], rp_wn2[20];
#pragma unroll
    for (int kk = 0; kk < 20; ++kk) {
        uint4 tp = rabw4[((24 * qi + kk) << 8) + j];
        rp_a2[kk] = tp.x; rp_b2[kk] = tp.y; rp_wp2[kk] = tp.z; rp_wn2[kk] = tp.w;
    }
    // streamed row-pairs 24qi+20..23, re-read from L2 each unfold
    const uint4* rstream = rabw4 + (((24 * qi + 20) << 8) + j);

    const float cmtu = cmt_g[u], gnu = gnum_g[u], cdu = cden_g[u];
    const float hwu = halt_w[u], owu = out_w[u], obu = out_b[u];
    const float hb = halt_b[0];
    float iw = 0.f, ibv = 0.f;
    if (tid < SS) { iw = input_w[tid]; ibv = input_b[tid]; }

    float v = 0.0f;
    int vhb = 0;                  // f16 bits of v (for readlane broadcast)
    float pond = 0.0f;
    __syncthreads();

    for (int t = 0; t < TT; ++t) {
        // ---- input mapping (f16 for broadcast use) ----
        if (tid < SS)
            ((__half*)xinh2)[tid] =
                __float2half(fmaf(x[((size_t)b * TT + t) * SS + tid], iw, ibv));
        __syncthreads();
        if (tid == 0) viol[0] = 0;

        // ---- sensory partials: row-pairs [16qi, 16qi+16), streamed from L2 ----
        {
            float P = 0.f, N = 0.f;
            __half2 accP2 = uh(0u), accN2 = uh(0u);
#pragma unroll 1
            for (int c = 0; c < 8; ++c) {
                int p0 = 16 * qi + 2 * c;
                uint4 q0 = sabw4[(p0 << 8) + j];
                uint4 q1 = sabw4[((p0 + 1) << 8) + j];
                u32 x0 = hu(xinh2[p0]);
                u32 x1 = hu(xinh2[p0 + 1]);
                STEP2(q0.x, q0.y, q0.z, q0.w, x0);
                STEP2(q1.x, q1.y, q1.z, q1.w, x1);
                if ((c & 3) == 3) FLUSH2();
            }
            part[0][qi][j] = make_float2(P, N);
        }
        __syncthreads();
        float basen, based;
        {
            float2 s0 = part[0][0][u], s1 = part[0][1][u];
            float2 s2 = part[0][2][u], s3 = part[0][3][u];
            float Ps = s0.x + s1.x + s2.x + s3.x;
            float Ns = s0.y + s1.y + s2.y + s3.y;
            basen = (Ps - Ns) + gnu;
            based = (Ps + Ns) + cdu;
        }

        int pb = 1;
        float accA = 0.0f, halt_sum = 0.0f, rem = 0.0f;
        int nupd = 0;
        int g3 = 0, g = 0;
        bool tconv = false;
        float pr = 0.0f;

        // ---- ACT loop (uniform early exit) ----
#pragma unroll 1
        for (int n = 0; n < 10; ++n) {
            bool ran = !tconv;
            if (ran) {
#pragma unroll 1
                for (int uu = 0; uu < 6 && !tconv; ++uu) {
                    // pair-packed v broadcast: even lane l holds (v[u(l)], v[u(l+1)])
                    int nbv = __shfl_xor(vhb, 1, 64);
                    int vpk = (vhb & 0xffff) | (nbv << 16);

                    float P = 0.f, N = 0.f;
                    __half2 accP2 = uh(0u), accN2 = uh(0u);
#pragma unroll
                    for (int kk = 0; kk < 20; ++kk) {
                        u32 v2 = (u32)__builtin_amdgcn_readlane(vpk, 2 * kk);
                        STEP2(rp_a2[kk], rp_b2[kk], rp_wp2[kk], rp_wn2[kk], v2);
                        if ((kk & 7) == 7) FLUSH2();   // kk=7,15 -> 4 pairs carry over
                    }
                    {   // streamed pairs 20..23 (lanes 40..46): 4 + 4 carried = 8 -> flush
                        uint4 s0 = rstream[0];
                        uint4 s1 = rstream[256];
                        uint4 s2 = rstream[512];
                        uint4 s3 = rstream[768];
                        u32 v2;
                        v2 = (u32)__builtin_amdgcn_readlane(vpk, 40);
                        STEP2(s0.x, s0.y, s0.z, s0.w, v2);
                        v2 = (u32)__builtin_amdgcn_readlane(vpk, 42);
                        STEP2(s1.x, s1.y, s1.z, s1.w, v2);
                        v2 = (u32)__builtin_amdgcn_readlane(vpk, 44);
                        STEP2(s2.x, s2.y, s2.z, s2.w, v2);
                        v2 = (u32)__builtin_amdgcn_readlane(vpk, 46);
                        STEP2(s3.x, s3.y, s3.z, s3.w, v2);
                        FLUSH2();
                    }
#pragma unroll
                    for (int m = 0; m < 8; ++m) {
                        uint4 prr = rlds4[((8 * qi + m) << 8) + j];
                        u32 v2 = (u32)__builtin_amdgcn_readlane(vpk, 48 + 2 * m);
                        STEP2(prr.x, prr.y, prr.z, prr.w, v2);
                    }
                    FLUSH2();
                    part[pb][qi][j] = make_float2(P, N);
                    __syncthreads();
                    // redundant per-wave v-update for own units
                    float2 p0 = part[pb][0][u], p1 = part[pb][1][u];
                    float2 p2 = part[pb][2][u], p3 = part[pb][3][u];
                    float Pt = p0.x + p1.x + p2.x + p3.x;
                    float Nt = p0.y + p1.y + p2.y + p3.y;
                    float num = (Pt - Nt) + basen;
                    float den = (Pt + Nt) + based;
                    float vn = fmaf(cmtu, v, num) * __builtin_amdgcn_rcpf(den);
                    float dv = fabsf(vn - v);
                    v = vn;
                    vhb = (int)__half_as_ushort(__float2half(v));
                    // convergence bookkeeping (triple-buffered flag, lag 1)
                    int aw = __all(dv <= CONV_EPS);
                    if (l == 0 && !aw) viol[g3] = 1;
                    int gz = g3 + 1; if (gz == 3) gz = 0;
                    if (tid == 0) viol[gz] = 0;
                    if (g >= 1) {
                        int gr = g3 - 1; if (gr < 0) gr = 2;
                        if (viol[gr] == 0) tconv = true;
                    }
                    pb ^= 1; ++g; g3 = gz;
                }

                // halting p = sigmoid(v . halt_w + hb); qj==0 waves hold all 256 units
                if (qj == 0) {
                    float hp = v * hwu;
                    hp += __shfl_down(hp, 32, 64);
                    hp += __shfl_down(hp, 16, 64);
                    hp += __shfl_down(hp, 8, 64);
                    hp += __shfl_down(hp, 4, 64);
                    hp += __shfl_down(hp, 2, 64);
                    hp += __shfl_down(hp, 1, 64);
                    if (l == 0) red[qi] = hp;
                }
                __syncthreads();
                float dot = red[0] + red[1] + red[2] + red[3] + hb;
                pr = __builtin_amdgcn_rcpf(1.0f + __builtin_amdgcn_exp2f(-dot * LOG2E));
            }
            // scalar ACT accounting (exact reference semantics)
            float new_sum = halt_sum + pr;
            bool halting = (n == 9) || (new_sum >= 0.99f);
            float r = 1.0f - halt_sum;
            float wgt = halting ? r : pr;
            accA = fmaf(wgt, v, accA);
            if (halting) rem += r;
            halt_sum = new_sum;
            ++nupd;
            if (halting) break;
        }

        // ---- t epilogue: new_state = accA ----
        if (qj == 0)
            readout[((size_t)b * TT + t) * UU + u] = fmaf(accA, owu, obu);
        v = accA;
        vhb = (int)__half_as_ushort(__float2half(v));
        pond += (float)nupd + rem;
    }

    if (qj == 0) h_state[(size_t)b * UU + u] = v;
    if (tid == 0) atomicAdd(ponder_out, pond * (1.0f / BB));
}

// ---------------- launch ----------------
extern "C" void kernel_launch(void* const* d_in, const int* in_sizes, int n_in,
                              void* d_out, int out_size, void* d_ws, size_t ws_size,
                              hipStream_t stream)
{
    const float* x             = (const float*)d_in[0];
    const float* input_w       = (const float*)d_in[1];
    const float* input_b       = (const float*)d_in[2];
    const float* sensory_w     = (const float*)d_in[3];
    const float* sensory_mu    = (const float*)d_in[4];
    const float* sensory_sigma = (const float*)d_in[5];
    const float* sensory_erev  = (const float*)d_in[6];
    const float* w             = (const float*)d_in[7];
    const float* mu            = (const float*)d_in[8];
    const float* sigma         = (const float*)d_in[9];
    const float* erev          = (const float*)d_in[10];
    const float* gleak         = (const float*)d_in[11];
    const float* vleak         = (const float*)d_in[12];
    const float* cm            = (const float*)d_in[13];
    const float* output_w      = (const float*)d_in[14];
    const float* output_b      = (const float*)d_in[15];
    const float* halt_w        = (const float*)d_in[16];
    const float* halt_b        = (const float*)d_in[17];

    float* readout = (float*)d_out;
    float* h_state = readout + (size_t)BB * TT * UU;
    float* ponder  = h_state + (size_t)BB * UU;

    char* wsb = (char*)d_ws;
    uint4* rabw4 = (uint4*)wsb;  wsb += (size_t)(UU / 2) * UU * sizeof(uint4);
    uint4* sabw4 = (uint4*)wsb;  wsb += (size_t)(SS / 2) * UU * sizeof(uint4);
    float* cmt  = (float*)wsb;  wsb += (size_t)UU * 4;
    float* gnum = (float*)wsb;  wsb += (size_t)UU * 4;
    float* cden = (float*)wsb;  wsb += (size_t)UU * 4;

    (void)hipMemsetAsync(ponder, 0, sizeof(float), stream);
    prep_kernel<<<128, 256, 0, stream>>>(
        sensory_w, sensory_mu, sensory_sigma, sensory_erev,
        w, mu, sigma, erev, gleak, vleak, cm,
        rabw4, sabw4, cmt, gnum, cden);
    ltc_kernel<<<BB, 1024, 0, stream>>>(
        x, input_w, input_b, halt_w, halt_b, output_w, output_b,
        rabw4, sabw4, cmt, gnum, cden,
        readout, h_state, ponder);
}

// Round 7
// 3699.426 us; speedup vs baseline: 1.4782x; 1.4661x over previous
//
#include <hip/hip_runtime.h>
#include <hip/hip_fp16.h>

#define LOG2E 1.44269504088896340736f
#define BB 256
#define TT 128
#define SS 128
#define UU 256
// |dv| threshold for "unfold was identity". Raised 6e-4 -> 1.2e-3 (R7): post-freeze
// drift is bounded by eps*c/(1-c) with contraction c = cm_t/den ~ 0.03-0.07, i.e.
// <= ~9e-5 -- far below f16 broadcast noise. Catches convergence one unfold earlier
// when dv lands in [6e-4, 1.2e-3]. Must stay above 1 f16 ulp of v (4.88e-4 dither).
#define CONV_EPS 1.2e-3f

typedef unsigned int u32;

__device__ __forceinline__ __half2 uh(u32 x) { union { u32 u; __half2 h; } c; c.u = x; return c.h; }
__device__ __forceinline__ u32 hu(__half2 h) { union { u32 u; __half2 h2; } c; c.h2 = h; return c.u; }

// ---------------- parameter precompute (pair-packed) ----------------
// sigmoid(sigma*(v-mu)) = 1/(1+2^(a*v+b)), a=-sigma*log2e, b=sigma*mu*log2e
// Two consecutive pre-rows (2*i2, 2*i2+1) packed per entry:
//   uint4{ half2(a0,a1), half2(b0,b1), half2(wP0,wP1), half2(wN0,wN1) }  (16 B)
__global__ __launch_bounds__(256) void prep_kernel(
    const float* __restrict__ sensory_w, const float* __restrict__ sensory_mu,
    const float* __restrict__ sensory_sigma, const float* __restrict__ sensory_erev,
    const float* __restrict__ w, const float* __restrict__ mu,
    const float* __restrict__ sigma, const float* __restrict__ erev,
    const float* __restrict__ gleak, const float* __restrict__ vleak,
    const float* __restrict__ cm,
    uint4* __restrict__ rabw4, uint4* __restrict__ sabw4,
    float* __restrict__ cmt, float* __restrict__ gnum, float* __restrict__ cden)
{
    int e = blockIdx.x * 256 + threadIdx.x;   // e = i2*256 + j
    if (e < (UU / 2) * UU) {
        int i2 = e >> 8, j = e & 255;
        int r0 = (2 * i2) * UU + j, r1 = r0 + UU;
        float sg0 = sigma[r0], sg1 = sigma[r1];
        float m0 = mu[r0], m1 = mu[r1];
        float wq0 = log1pf(expf(w[r0])), wq1 = log1pf(expf(w[r1]));
        bool p0 = erev[r0] > 0.0f, p1 = erev[r1] > 0.0f;
        uint4 o;
        o.x = hu(__floats2half2_rn(-sg0 * LOG2E, -sg1 * LOG2E));
        o.y = hu(__floats2half2_rn(sg0 * m0 * LOG2E, sg1 * m1 * LOG2E));
        o.z = hu(__floats2half2_rn(p0 ? wq0 : 0.0f, p1 ? wq1 : 0.0f));
        o.w = hu(__floats2half2_rn(p0 ? 0.0f : wq0, p1 ? 0.0f : wq1));
        rabw4[e] = o;
    }
    if (e < (SS / 2) * UU) {
        int i2 = e >> 8, j = e & 255;
        int r0 = (2 * i2) * UU + j, r1 = r0 + UU;
        float sg0 = sensory_sigma[r0], sg1 = sensory_sigma[r1];
        float m0 = sensory_mu[r0], m1 = sensory_mu[r1];
        float wq0 = log1pf(expf(sensory_w[r0])), wq1 = log1pf(expf(sensory_w[r1]));
        bool p0 = sensory_erev[r0] > 0.0f, p1 = sensory_erev[r1] > 0.0f;
        uint4 o;
        o.x = hu(__floats2half2_rn(-sg0 * LOG2E, -sg1 * LOG2E));
        o.y = hu(__floats2half2_rn(sg0 * m0 * LOG2E, sg1 * m1 * LOG2E));
        o.z = hu(__floats2half2_rn(p0 ? wq0 : 0.0f, p1 ? wq1 : 0.0f));
        o.w = hu(__floats2half2_rn(p0 ? 0.0f : wq0, p1 ? 0.0f : wq1));
        sabw4[e] = o;
    }
    if (e < UU) {
        float gl = log1pf(expf(gleak[e]));
        float c = log1pf(expf(cm[e])) * 6.0f;   // ODE_UNFOLDS=6, ts=1
        cmt[e] = c;
        gnum[e] = gl * vleak[e];
        cden[e] = c + gl + 1e-8f;
    }
}

// Hybrid packed 2-row sigmoid-weighted accumulation (R7).
// R6 established f16 transcendentals are ~quarter-rate: all-full-rate bit-trick glue
// costs the same cycles as 2x{exp,rcp}. So keep the scalar transcendentals (minimal
// temps, no spill, hrcp(inf)=0 saturates safely -> NO clamp needed) and take only the
// packing wins: one pk-fma for both z's, packed (P,N) accumulate, b128 param loads.
#define STEP2(A2U, B2U, WP2U, WN2U, V2U) do {                                \
    u32 z_ = hu(__hfma2(uh(A2U), uh(V2U), uh(B2U)));                         \
    __half el_ = hexp2(__ushort_as_half((unsigned short)(z_ & 0xffffu)));    \
    __half eh_ = hexp2(__ushort_as_half((unsigned short)(z_ >> 16)));        \
    __half dl_ = __hadd(el_, __float2half(1.0f));                            \
    __half dh_ = __hadd(eh_, __float2half(1.0f));                            \
    __half2 s2_ = __halves2half2(hrcp(dl_), hrcp(dh_));                      \
    accP2 = __hfma2(uh(WP2U), s2_, accP2);                                   \
    accN2 = __hfma2(uh(WN2U), s2_, accN2);                                   \
} while (0)

#define FLUSH2() do {                                                        \
    float2 fp_ = __half22float2(accP2);                                      \
    float2 fn_ = __half22float2(accN2);                                      \
    P += fp_.x + fp_.y; N += fn_.x + fn_.y;                                  \
    accP2 = uh(0u); accN2 = uh(0u);                                          \
} while (0)

// ---------------- main kernel: 1 block = 1 batch element, 16 waves ----------------
// wave (qi=wv&3, qj=wv>>2): column j = 64*qj + l.
// Recurrent row-pairs per wave: 24 in registers (pairs 24qi..+23 = rows 48qi..+47,
// 96 VGPRs) + 8 from LDS (pairs 96+8qi..+7 = rows 192+16qi..+15). v lane-distributed:
// lane l holds v[u(l)]; pair-packed v broadcast built once per unfold with one
// shfl_xor (even lane l holds (v[u(l)],v[u(l+1)])); one readlane feeds each STEP2.
// 1 barrier per unfold. Convergence skip via triple-buffered viol flag (lag 1).
__global__ __launch_bounds__(1024, 4) void ltc_kernel(
    const float* __restrict__ x,
    const float* __restrict__ input_w, const float* __restrict__ input_b,
    const float* __restrict__ halt_w, const float* __restrict__ halt_b,
    const float* __restrict__ out_w, const float* __restrict__ out_b,
    const uint4* __restrict__ rabw4, const uint4* __restrict__ sabw4,
    const float* __restrict__ cmt_g, const float* __restrict__ gnum_g,
    const float* __restrict__ cden_g,
    float* __restrict__ readout, float* __restrict__ h_state, float* __restrict__ ponder_out)
{
    const int b = blockIdx.x, tid = threadIdx.x;
    const int wv = tid >> 6, l = tid & 63;
    const int qi = wv & 3, qj = wv >> 2;
    const int j = (qj << 6) + l;
    const int u = (l < 48) ? (48 * qi + l) : (192 + 16 * qi + (l - 48));

    __shared__ uint4 rlds4[32 * UU];         // 128 KB: row-pairs 96..127 (rows 192..255)
    __shared__ float2 part[2][4][UU];        // 16 KB: (P,N) partials, double-buffered
    __shared__ __half2 xinh2[SS / 2];
    __shared__ float red[4];
    __shared__ int viol[3];                  // triple-buffered "unfold changed v" flag

    // stage LDS-resident row-pairs (once): 32*256 uint4
    for (int m = 0; m < 8; ++m) {
        int f = m * 1024 + tid;
        rlds4[f] = rabw4[96 * 256 + f];
    }

    // register-resident row-pairs (once): 96 VGPRs (pairs 24qi..24qi+23)
    u32 rp_a2[24], rp_b2[24], rp_wp2[24], rp_wn2[24];
#pragma unroll
    for (int kk = 0; kk < 24; ++kk) {
        uint4 tp = rabw4[((24 * qi + kk) << 8) + j];
        rp_a2[kk] = tp.x; rp_b2[kk] = tp.y; rp_wp2[kk] = tp.z; rp_wn2[kk] = tp.w;
    }

    const float cmtu = cmt_g[u], gnu = gnum_g[u], cdu = cden_g[u];
    const float hwu = halt_w[u], owu = out_w[u], obu = out_b[u];
    const float hb = halt_b[0];
    float iw = 0.f, ibv = 0.f;
    if (tid < SS) { iw = input_w[tid]; ibv = input_b[tid]; }

    float v = 0.0f;
    int vhb = 0;                  // f16 bits of v (for readlane broadcast)
    float pond = 0.0f;
    __syncthreads();

    for (int t = 0; t < TT; ++t) {
        // ---- input mapping (f16 for broadcast use) ----
        if (tid < SS)
            ((__half*)xinh2)[tid] =
                __float2half(fmaf(x[((size_t)b * TT + t) * SS + tid], iw, ibv));
        __syncthreads();
        if (tid == 0) viol[0] = 0;

        // ---- sensory partials: row-pairs [16qi, 16qi+16), streamed from L2 ----
        {
            float P = 0.f, N = 0.f;
            __half2 accP2 = uh(0u), accN2 = uh(0u);
#pragma unroll 1
            for (int c = 0; c < 8; ++c) {
                int p0 = 16 * qi + 2 * c;
                uint4 q0 = sabw4[(p0 << 8) + j];
                uint4 q1 = sabw4[((p0 + 1) << 8) + j];
                u32 x0 = hu(xinh2[p0]);
                u32 x1 = hu(xinh2[p0 + 1]);
                STEP2(q0.x, q0.y, q0.z, q0.w, x0);
                STEP2(q1.x, q1.y, q1.z, q1.w, x1);
                if ((c & 3) == 3) FLUSH2();
            }
            part[0][qi][j] = make_float2(P, N);
        }
        __syncthreads();
        float basen, based;
        {
            float2 s0 = part[0][0][u], s1 = part[0][1][u];
            float2 s2 = part[0][2][u], s3 = part[0][3][u];
            float Ps = s0.x + s1.x + s2.x + s3.x;
            float Ns = s0.y + s1.y + s2.y + s3.y;
            basen = (Ps - Ns) + gnu;
            based = (Ps + Ns) + cdu;
        }

        int pb = 1;
        float accA = 0.0f, halt_sum = 0.0f, rem = 0.0f;
        int nupd = 0;
        int g3 = 0, g = 0;
        bool tconv = false;
        float pr = 0.0f;

        // ---- ACT loop (uniform early exit) ----
#pragma unroll 1
        for (int n = 0; n < 10; ++n) {
            bool ran = !tconv;
            if (ran) {
#pragma unroll 1
                for (int uu = 0; uu < 6 && !tconv; ++uu) {
                    // pair-packed v broadcast: even lane l holds (v[u(l)], v[u(l+1)])
                    int nbv = __shfl_xor(vhb, 1, 64);
                    int vpk = (vhb & 0xffff) | (nbv << 16);

                    float P = 0.f, N = 0.f;
                    __half2 accP2 = uh(0u), accN2 = uh(0u);
#pragma unroll
                    for (int kk = 0; kk < 24; ++kk) {
                        u32 v2 = (u32)__builtin_amdgcn_readlane(vpk, 2 * kk);
                        STEP2(rp_a2[kk], rp_b2[kk], rp_wp2[kk], rp_wn2[kk], v2);
                        if ((kk & 7) == 7) FLUSH2();
                    }
#pragma unroll
                    for (int m = 0; m < 8; ++m) {
                        uint4 prr = rlds4[((8 * qi + m) << 8) + j];
                        u32 v2 = (u32)__builtin_amdgcn_readlane(vpk, 48 + 2 * m);
                        STEP2(prr.x, prr.y, prr.z, prr.w, v2);
                    }
                    FLUSH2();
                    part[pb][qi][j] = make_float2(P, N);
                    __syncthreads();
                    // redundant per-wave v-update for own units
                    float2 p0 = part[pb][0][u], p1 = part[pb][1][u];
                    float2 p2 = part[pb][2][u], p3 = part[pb][3][u];
                    float Pt = p0.x + p1.x + p2.x + p3.x;
                    float Nt = p0.y + p1.y + p2.y + p3.y;
                    float num = (Pt - Nt) + basen;
                    float den = (Pt + Nt) + based;
                    float vn = fmaf(cmtu, v, num) * __builtin_amdgcn_rcpf(den);
                    float dv = fabsf(vn - v);
                    v = vn;
                    vhb = (int)__half_as_ushort(__float2half(v));
                    // convergence bookkeeping (triple-buffered flag, lag 1)
                    int aw = __all(dv <= CONV_EPS);
                    if (l == 0 && !aw) viol[g3] = 1;
                    int gz = g3 + 1; if (gz == 3) gz = 0;
                    if (tid == 0) viol[gz] = 0;
                    if (g >= 1) {
                        int gr = g3 - 1; if (gr < 0) gr = 2;
                        if (viol[gr] == 0) tconv = true;
                    }
                    pb ^= 1; ++g; g3 = gz;
                }

                // halting p = sigmoid(v . halt_w + hb); qj==0 waves hold all 256 units
                if (qj == 0) {
                    float hp = v * hwu;
                    hp += __shfl_down(hp, 32, 64);
                    hp += __shfl_down(hp, 16, 64);
                    hp += __shfl_down(hp, 8, 64);
                    hp += __shfl_down(hp, 4, 64);
                    hp += __shfl_down(hp, 2, 64);
                    hp += __shfl_down(hp, 1, 64);
                    if (l == 0) red[qi] = hp;
                }
                __syncthreads();
                float dot = red[0] + red[1] + red[2] + red[3] + hb;
                pr = __builtin_amdgcn_rcpf(1.0f + __builtin_amdgcn_exp2f(-dot * LOG2E));
            }
            // scalar ACT accounting (exact reference semantics)
            float new_sum = halt_sum + pr;
            bool halting = (n == 9) || (new_sum >= 0.99f);
            float r = 1.0f - halt_sum;
            float wgt = halting ? r : pr;
            accA = fmaf(wgt, v, accA);
            if (halting) rem += r;
            halt_sum = new_sum;
            ++nupd;
            if (halting) break;
        }

        // ---- t epilogue: new_state = accA ----
        if (qj == 0)
            readout[((size_t)b * TT + t) * UU + u] = fmaf(accA, owu, obu);
        v = accA;
        vhb = (int)__half_as_ushort(__float2half(v));
        pond += (float)nupd + rem;
    }

    if (qj == 0) h_state[(size_t)b * UU + u] = v;
    if (tid == 0) atomicAdd(ponder_out, pond * (1.0f / BB));
}

// ---------------- launch ----------------
extern "C" void kernel_launch(void* const* d_in, const int* in_sizes, int n_in,
                              void* d_out, int out_size, void* d_ws, size_t ws_size,
                              hipStream_t stream)
{
    const float* x             = (const float*)d_in[0];
    const float* input_w       = (const float*)d_in[1];
    const float* input_b       = (const float*)d_in[2];
    const float* sensory_w     = (const float*)d_in[3];
    const float* sensory_mu    = (const float*)d_in[4];
    const float* sensory_sigma = (const float*)d_in[5];
    const float* sensory_erev  = (const float*)d_in[6];
    const float* w             = (const float*)d_in[7];
    const float* mu            = (const float*)d_in[8];
    const float* sigma         = (const float*)d_in[9];
    const float* erev          = (const float*)d_in[10];
    const float* gleak         = (const float*)d_in[11];
    const float* vleak         = (const float*)d_in[12];
    const float* cm            = (const float*)d_in[13];
    const float* output_w      = (const float*)d_in[14];
    const float* output_b      = (const float*)d_in[15];
    const float* halt_w        = (const float*)d_in[16];
    const float* halt_b        = (const float*)d_in[17];

    float* readout = (float*)d_out;
    float* h_state = readout + (size_t)BB * TT * UU;
    float* ponder  = h_state + (size_t)BB * UU;

    char* wsb = (char*)d_ws;
    uint4* rabw4 = (uint4*)wsb;  wsb += (size_t)(UU / 2) * UU * sizeof(uint4);
    uint4* sabw4 = (uint4*)wsb;  wsb += (size_t)(SS / 2) * UU * sizeof(uint4);
    float* cmt  = (float*)wsb;  wsb += (size_t)UU * 4;
    float* gnum = (float*)wsb;  wsb += (size_t)UU * 4;
    float* cden = (float*)wsb;  wsb += (size_t)UU * 4;

    (void)hipMemsetAsync(ponder, 0, sizeof(float), stream);
    prep_kernel<<<128, 256, 0, stream>>>(
        sensory_w, sensory_mu, sensory_sigma, sensory_erev,
        w, mu, sigma, erev, gleak, vleak, cm,
        rabw4, sabw4, cmt, gnum, cden);
    ltc_kernel<<<BB, 1024, 0, stream>>>(
        x, input_w, input_b, halt_w, halt_b, output_w, output_b,
        rabw4, sabw4, cmt, gnum, cden,
        readout, h_state, ponder);
}